// Round 13
// baseline (190.295 us; speedup 1.0000x reference)
//
#include <hip/hip_runtime.h>
#include <hip/hip_bf16.h>
#include <cstddef>

#define D 128
#define SHIFT 9           // coarse bucket = 512 nodes
#define RN (1 << SHIFT)
#define CAPLOG 14         // per-bucket capacity 16384 (avg padded ~12288)
#define CAP (1 << CAPLOG)

typedef __attribute__((ext_vector_type(8))) short bf16x8;
typedef __attribute__((ext_vector_type(16))) float f32x16;
typedef __attribute__((ext_vector_type(4))) float f32x4;
typedef __attribute__((ext_vector_type(4))) int i32x4;

static __device__ __forceinline__ unsigned short f2bf(float f) {
  return __builtin_bit_cast(unsigned short, __float2bfloat16(f));
}
static __device__ __forceinline__ float bflo(unsigned u) {
  return __uint_as_float(u << 16);
}
static __device__ __forceinline__ float bfhi(unsigned u) {
  return __uint_as_float(u & 0xffff0000u);
}

// init gcursor, zero dummy g row (row n), pre-convert W to bf16 (one-time)
__global__ void k_init(int* __restrict__ gcursor, int nc, unsigned* __restrict__ gz,
                       const float* __restrict__ W, unsigned short* __restrict__ Wbf) {
  const int t = blockIdx.x * 256 + threadIdx.x;
  if (t < nc) gcursor[t] = t << CAPLOG;
  if (t < 64) gz[t] = 0;  // 128 bf16 = 64 uints
  if (t < 128 * 128) Wbf[t] = f2bf(W[t]);
}

// block-local counting sort into coarse buckets. Per-wave LDS hists. One
// gcursor atomic per (block,bucket) claims a contiguous run written by THIS
// block -> line-dense write-back. pairs packed 4B: src(22b) | ldst(9b)<<22.
__global__ __launch_bounds__(256) void k_psort(
    const int* __restrict__ src, const int* __restrict__ dst,
    int* __restrict__ gcursor, unsigned* __restrict__ pairs, int e, int nc) {
  __shared__ int hist4[4][256];
  const int tid = threadIdx.x;
  const int w = tid >> 6;
  const int base = blockIdx.x * 4096;
  const int m = min(4096, e - base);
#pragma unroll
  for (int u = 0; u < 4; ++u) ((int*)hist4)[tid + 256 * u] = 0;
  __syncthreads();
  int myd[16], mys[16];
#pragma unroll
  for (int j = 0; j < 4; ++j) {
    const int i4 = tid + j * 256;          // int4 index within block (0..1023)
    const int i = i4 * 4;                  // edge offset within block
    if (i + 3 < m) {
      const i32x4 d4 = __builtin_nontemporal_load(
          reinterpret_cast<const i32x4*>(dst + base) + i4);
      const i32x4 s4 = __builtin_nontemporal_load(
          reinterpret_cast<const i32x4*>(src + base) + i4);
#pragma unroll
      for (int u = 0; u < 4; ++u) {
        myd[j * 4 + u] = d4[u]; mys[j * 4 + u] = s4[u];
        atomicAdd(&hist4[w][d4[u] >> SHIFT], 1);
      }
    } else {
#pragma unroll
      for (int u = 0; u < 4; ++u) {
        const int ii = i + u;
        if (ii < m) {
          myd[j * 4 + u] = dst[base + ii];
          mys[j * 4 + u] = src[base + ii];
          atomicAdd(&hist4[w][myd[j * 4 + u] >> SHIFT], 1);
        } else {
          myd[j * 4 + u] = -1;
        }
      }
    }
  }
  __syncthreads();
  if (tid < nc) {
    const int t0 = hist4[0][tid], t1 = hist4[1][tid];
    const int t2 = hist4[2][tid], t3 = hist4[3][tid];
    const int tot = t0 + t1 + t2 + t3;
    int b = (tot > 0) ? atomicAdd(&gcursor[tid], tot) : 0;
    hist4[0][tid] = b;
    hist4[1][tid] = b + t0;
    hist4[2][tid] = b + t0 + t1;
    hist4[3][tid] = b + t0 + t1 + t2;
  }
  __syncthreads();
#pragma unroll
  for (int j = 0; j < 16; ++j) {
    if (myd[j] >= 0) {
      const int c = myd[j] >> SHIFT;
      const int pos = atomicAdd(&hist4[w][c], 1);
      const unsigned pk = (unsigned)mys[j] | ((unsigned)(myd[j] & (RN - 1)) << 22);
      __builtin_nontemporal_store(pk, &pairs[pos]);
    }
  }
}

// one block per bucket: LDS histogram -> degrees (dinv, cnt), local scan ->
// rowptr (padded to x16), then scatter srcs + pad with dummy src=n (zero row).
__global__ __launch_bounds__(512) void k_fine(
    const unsigned* __restrict__ pairs, const int* __restrict__ gcursor,
    int* __restrict__ rowptr, int* __restrict__ cnt, float* __restrict__ dinv,
    int* __restrict__ srcs, int n) {
  __shared__ int hist[RN];
  __shared__ int rowL[RN];
  __shared__ int sdata[RN];
  const int c = blockIdx.x;
  const int tid = threadIdx.x;
  const int node0 = c << SHIFT;
  const int nodes = min(RN, n - node0);
  hist[tid] = 0;
  __syncthreads();
  const int beg = c << CAPLOG;
  const int end = gcursor[c];
  for (int i = beg + tid; i < end; i += RN)
    atomicAdd(&hist[__builtin_nontemporal_load(&pairs[i]) >> 22], 1);
  __syncthreads();
  const int deg = hist[tid];
  const int p = (deg + 15) & ~15;  // pad to x16 -> accum runs 16-edge groups
  sdata[tid] = p;
  __syncthreads();
  for (int off = 1; off < RN; off <<= 1) {
    int t = (tid >= off) ? sdata[tid - off] : 0;
    __syncthreads();
    sdata[tid] += t;
    __syncthreads();
  }
  const int rbase = beg + sdata[tid] - p;
  rowL[tid] = rbase;
  hist[tid] = rbase;
  if (tid < nodes) {
    rowptr[node0 + tid] = rbase;
    cnt[node0 + tid] = p;
    dinv[node0 + tid] = fminf(rsqrtf((float)(deg + 1)), 1.0e6f);
  }
  __syncthreads();
  for (int i = beg + tid; i < end; i += RN) {
    const unsigned pr = __builtin_nontemporal_load(&pairs[i]);
    const int pos = atomicAdd(&hist[pr >> 22], 1);
    srcs[pos] = (int)(pr & 0x3FFFFFu);
  }
  __syncthreads();
  const int fend = rowL[tid] + p;
  for (int i = hist[tid]; i < fend; ++i) srcs[i] = n;  // dummy -> zero row
}

// g(bf16) = (x @ W^T + b) * dinv[r] via mfma_f32_32x32x16_bf16.
// A=W-frag (held in REGISTERS, loaded once from L2-resident Wbf), B=x-frag
// from a 32KB swizzled LDS tile. Lane holds one x-row; regs hold 4 consecutive
// cols -> packed uint2 epilogue stores.
__global__ __launch_bounds__(256) void k_gemm(
    const float* __restrict__ x, const unsigned short* __restrict__ Wbf,
    const float* __restrict__ bias, const float* __restrict__ dinv,
    __hip_bfloat16* __restrict__ g, int n) {
  __shared__ unsigned short xs[128 * 128];
  const int tid = threadIdx.x;
  const int row0 = blockIdx.x * 128;
  const int lane = tid & 63;
  const int wv = tid >> 6;
  const int xr0 = (wv >> 1) * 64;  // x-row tile offset
  const int cc0 = (wv & 1) * 64;   // col tile offset
  const int lr = lane & 31;
  const int lk = lane >> 5;

  // W fragments -> registers (64 VGPR), once per wave. Wbf linear: element
  // offset for (ks, lk) = ks*16 + lk*8 (matches the mfma A-frag layout).
  bf16x8 Wf[2][8];
#pragma unroll
  for (int p = 0; p < 2; ++p) {
    const int r = cc0 + p * 32 + lr;
#pragma unroll
    for (int ks = 0; ks < 8; ++ks)
      Wf[p][ks] = *reinterpret_cast<const bf16x8*>(&Wbf[r * 128 + ks * 16 + lk * 8]);
  }

  // stage x tile: f32 -> bf16, XOR-swizzled chunks
#pragma unroll
  for (int u = 0; u < 8; ++u) {
    const int f = tid + 256 * u;   // 0..2047
    const int row = f >> 4;        // 0..127
    const int c = f & 15;          // 16B chunk (8 bf16)
    const int ch = (c ^ (row & 7)) << 3;
    f32x4 v0 = {0.f, 0.f, 0.f, 0.f}, v1 = v0;
    if (row0 + row < n) {
      const f32x4* p = reinterpret_cast<const f32x4*>(&x[(size_t)(row0 + row) * D + c * 8]);
      v0 = __builtin_nontemporal_load(p);
      v1 = __builtin_nontemporal_load(p + 1);
    }
    uint4 pk;
    pk.x = f2bf(v0[0]) | ((unsigned)f2bf(v0[1]) << 16);
    pk.y = f2bf(v0[2]) | ((unsigned)f2bf(v0[3]) << 16);
    pk.z = f2bf(v1[0]) | ((unsigned)f2bf(v1[1]) << 16);
    pk.w = f2bf(v1[2]) | ((unsigned)f2bf(v1[3]) << 16);
    *reinterpret_cast<uint4*>(&xs[row * 128 + ch]) = pk;
  }
  __syncthreads();

  f32x16 acc[2][2];  // [p: col subtile][q: row subtile]
#pragma unroll
  for (int p = 0; p < 2; ++p)
#pragma unroll
    for (int q = 0; q < 2; ++q)
#pragma unroll
      for (int t = 0; t < 16; ++t) acc[p][q][t] = 0.f;

#pragma unroll
  for (int ks = 0; ks < 8; ++ks) {
    bf16x8 b[2];
#pragma unroll
    for (int q = 0; q < 2; ++q) {
      const int r = xr0 + q * 32 + lr;  // x row
      const int ch = ((ks * 2 + lk) ^ (r & 7)) << 3;
      b[q] = *reinterpret_cast<const bf16x8*>(&xs[r * 128 + ch]);
    }
#pragma unroll
    for (int p = 0; p < 2; ++p)
#pragma unroll
      for (int q = 0; q < 2; ++q)
        acc[p][q] = __builtin_amdgcn_mfma_f32_32x32x16_bf16(Wf[p][ks], b[q], acc[p][q], 0, 0, 0);
  }

  // D layout: lane = x-row (q*32+lr), reg -> col (reg&3) + 8*(reg>>2) + 4*lk
#pragma unroll
  for (int q = 0; q < 2; ++q) {
    const int r = row0 + xr0 + q * 32 + lr;
    if (r < n) {
      const float dv = dinv[r];
#pragma unroll
      for (int p = 0; p < 2; ++p) {
#pragma unroll
        for (int rg = 0; rg < 4; ++rg) {
          const int cb = cc0 + p * 32 + 8 * rg + 4 * lk;
          const float v0 = (acc[p][q][rg * 4 + 0] + bias[cb + 0]) * dv;
          const float v1 = (acc[p][q][rg * 4 + 1] + bias[cb + 1]) * dv;
          const float v2 = (acc[p][q][rg * 4 + 2] + bias[cb + 2]) * dv;
          const float v3 = (acc[p][q][rg * 4 + 3] + bias[cb + 3]) * dv;
          uint2 pk;
          pk.x = f2bf(v0) | ((unsigned)f2bf(v1) << 16);
          pk.y = f2bf(v2) | ((unsigned)f2bf(v3) << 16);
          *reinterpret_cast<uint2*>(&g[(size_t)r * D + cb]) = pk;
        }
      }
    }
  }
}

// one wave per node; 16-edge groups: half 0 (lanes 0-31) gathers even edges,
// half 1 odd edges, 8B/lane -> 8 independent gathers in flight. srcs for the
// NEXT group prefetched (nt int4 x4) during current gathers. num % 16 == 0.
__global__ __launch_bounds__(256) void k_accum(
    const int* __restrict__ rowptr, const int* __restrict__ cnt,
    const int* __restrict__ srcs, const uint2* __restrict__ gq,
    const float* __restrict__ dinv, float* __restrict__ out, int n) {
  const int w = (int)(((size_t)blockIdx.x * 256 + threadIdx.x) >> 6);
  const int lane = threadIdx.x & 63;
  if (w >= n) return;
  const int li = lane & 31;
  const int half = lane >> 5;
  const int beg = rowptr[w];
  const int num = cnt[w];

  // self term: half0 reads row w, half1 reads zero row n
  const uint2 sv = gq[(size_t)(half ? n : w) * 32 + li];
  float a0 = bflo(sv.x), a1 = bfhi(sv.x), a2 = bflo(sv.y), a3 = bfhi(sv.y);

  if (num > 0) {
    const i32x4* s4 = (const i32x4*)(srcs + beg);
    i32x4 q0 = __builtin_nontemporal_load(s4);
    i32x4 q1 = __builtin_nontemporal_load(s4 + 1);
    i32x4 q2 = __builtin_nontemporal_load(s4 + 2);
    i32x4 q3 = __builtin_nontemporal_load(s4 + 3);
    for (int k = 0; k < num; k += 16) {
      const int nx = (k + 16 < num) ? ((k + 16) >> 2) : 0;  // guarded prefetch
      const i32x4 n0 = __builtin_nontemporal_load(s4 + nx);
      const i32x4 n1 = __builtin_nontemporal_load(s4 + nx + 1);
      const i32x4 n2 = __builtin_nontemporal_load(s4 + nx + 2);
      const i32x4 n3 = __builtin_nontemporal_load(s4 + nx + 3);
      const int e0 = half ? q0[1] : q0[0], e1 = half ? q0[3] : q0[2];
      const int e2 = half ? q1[1] : q1[0], e3 = half ? q1[3] : q1[2];
      const int e4 = half ? q2[1] : q2[0], e5 = half ? q2[3] : q2[2];
      const int e6 = half ? q3[1] : q3[0], e7 = half ? q3[3] : q3[2];
      const uint2 t0 = gq[(size_t)e0 * 32 + li];
      const uint2 t1 = gq[(size_t)e1 * 32 + li];
      const uint2 t2 = gq[(size_t)e2 * 32 + li];
      const uint2 t3 = gq[(size_t)e3 * 32 + li];
      const uint2 t4 = gq[(size_t)e4 * 32 + li];
      const uint2 t5 = gq[(size_t)e5 * 32 + li];
      const uint2 t6 = gq[(size_t)e6 * 32 + li];
      const uint2 t7 = gq[(size_t)e7 * 32 + li];
      a0 += bflo(t0.x) + bflo(t1.x) + bflo(t2.x) + bflo(t3.x) +
            bflo(t4.x) + bflo(t5.x) + bflo(t6.x) + bflo(t7.x);
      a1 += bfhi(t0.x) + bfhi(t1.x) + bfhi(t2.x) + bfhi(t3.x) +
            bfhi(t4.x) + bfhi(t5.x) + bfhi(t6.x) + bfhi(t7.x);
      a2 += bflo(t0.y) + bflo(t1.y) + bflo(t2.y) + bflo(t3.y) +
            bflo(t4.y) + bflo(t5.y) + bflo(t6.y) + bflo(t7.y);
      a3 += bfhi(t0.y) + bfhi(t1.y) + bfhi(t2.y) + bfhi(t3.y) +
            bfhi(t4.y) + bfhi(t5.y) + bfhi(t6.y) + bfhi(t7.y);
      q0 = n0; q1 = n1; q2 = n2; q3 = n3;
    }
  }

  a0 += __shfl_xor(a0, 32);
  a1 += __shfl_xor(a1, 32);
  a2 += __shfl_xor(a2, 32);
  a3 += __shfl_xor(a3, 32);

  if (!half) {
    const float dv = dinv[w];
    f32x4 res;
    res[0] = a0 * dv; res[1] = a1 * dv; res[2] = a2 * dv; res[3] = a3 * dv;
    f32x4* dst = (f32x4*)(out + (size_t)w * D) + li;
    __builtin_nontemporal_store(res, dst);
  }
}

extern "C" void kernel_launch(void* const* d_in, const int* in_sizes, int n_in,
                              void* d_out, int out_size, void* d_ws, size_t ws_size,
                              hipStream_t stream) {
  const float* x = (const float*)d_in[0];
  const int* ei = (const int*)d_in[1];
  const float* W = (const float*)d_in[2];
  const float* b = (const float*)d_in[3];
  float* out = (float*)d_out;
  const int n = in_sizes[0] / D;
  const int e = in_sizes[1] / 2;
  const int* src = ei;      // edge_index[0]
  const int* dst = ei + e;  // edge_index[1]
  const int nc = (n + RN - 1) >> SHIFT;  // coarse buckets (196 for n=100k)

  char* ws = (char*)d_ws;
  const size_t nbb = ((size_t)n * 4 + 255) / 256 * 256;
  const size_t pb = (((size_t)nc << CAPLOG) * 4 + 255) / 256 * 256;
  float* dinv = (float*)ws;                         // n
  int* rowptr = (int*)(ws + nbb);                   // n
  int* cnt = (int*)(ws + 2 * nbb);                  // n (padded degree)
  int* gcursor = (int*)(ws + 3 * nbb);              // <=256 (1 KB)
  unsigned short* Wbf = (unsigned short*)(ws + 3 * nbb + 1024);  // 32 KB
  int* srcs = (int*)(ws + 3 * nbb + 1024 + 32768);  // nc*CAP ints
  char* pr_base = ws + 3 * nbb + 1024 + 32768 + pb;
  unsigned* pairs = (unsigned*)pr_base;             // nc*CAP uints (dead after fine)
  // g aliases pairs (gemm runs after fine); (n+1) rows, row n = zeros
  __hip_bfloat16* g = (__hip_bfloat16*)pr_base;

  k_init<<<64, 256, 0, stream>>>(gcursor, nc, (unsigned*)(g + (size_t)n * D), W, Wbf);
  k_psort<<<(e + 4095) / 4096, 256, 0, stream>>>(src, dst, gcursor, pairs, e, nc);
  k_fine<<<nc, RN, 0, stream>>>(pairs, gcursor, rowptr, cnt, dinv, srcs, n);
  k_gemm<<<(n + 127) / 128, 256, 0, stream>>>(x, Wbf, b, dinv, g, n);
  k_accum<<<(n + 3) / 4, 256, 0, stream>>>(rowptr, cnt, srcs, (const uint2*)g,
                                           dinv, out, n);
}

// Round 14
// 175.947 us; speedup vs baseline: 1.0815x; 1.0815x over previous
//
#include <hip/hip_runtime.h>
#include <hip/hip_bf16.h>
#include <cstddef>

#define D 128
#define SHIFT 9           // coarse bucket = 512 nodes
#define RN (1 << SHIFT)
#define CAPLOG 14         // per-bucket capacity 16384 (avg padded ~12288)
#define CAP (1 << CAPLOG)

typedef __attribute__((ext_vector_type(8))) short bf16x8;
typedef __attribute__((ext_vector_type(16))) float f32x16;
typedef __attribute__((ext_vector_type(4))) float f32x4;

static __device__ __forceinline__ unsigned short f2bf(float f) {
  return __builtin_bit_cast(unsigned short, __float2bfloat16(f));
}
static __device__ __forceinline__ float bflo(unsigned u) {
  return __uint_as_float(u << 16);
}
static __device__ __forceinline__ float bfhi(unsigned u) {
  return __uint_as_float(u & 0xffff0000u);
}

// init gcursor, zero dummy g row (row n), pre-convert W to bf16 (one-time)
__global__ void k_init(int* __restrict__ gcursor, int nc, unsigned* __restrict__ gz,
                       const float* __restrict__ W, unsigned short* __restrict__ Wbf) {
  const int t = blockIdx.x * 256 + threadIdx.x;
  if (t < nc) gcursor[t] = t << CAPLOG;
  if (t < 64) gz[t] = 0;  // 128 bf16 = 64 uints
  if (t < 128 * 128) Wbf[t] = f2bf(W[t]);
}

// block-local counting sort into coarse buckets. Per-wave LDS hists. One
// gcursor atomic per (block,bucket) claims a contiguous run written by THIS
// block -> line-dense write-back. pairs packed 4B: src(22b) | ldst(9b)<<22.
__global__ __launch_bounds__(256) void k_psort(
    const int* __restrict__ src, const int* __restrict__ dst,
    int* __restrict__ gcursor, unsigned* __restrict__ pairs, int e, int nc) {
  __shared__ int hist4[4][256];
  const int tid = threadIdx.x;
  const int w = tid >> 6;
  const int base = blockIdx.x * 4096;
  const int m = min(4096, e - base);
#pragma unroll
  for (int u = 0; u < 4; ++u) ((int*)hist4)[tid + 256 * u] = 0;
  __syncthreads();
  int myd[16], mys[16];
#pragma unroll
  for (int j = 0; j < 16; ++j) {
    const int i = tid + j * 256;
    if (i < m) {
      myd[j] = dst[base + i];
      mys[j] = src[base + i];
      atomicAdd(&hist4[w][myd[j] >> SHIFT], 1);
    }
  }
  __syncthreads();
  if (tid < nc) {
    const int t0 = hist4[0][tid], t1 = hist4[1][tid];
    const int t2 = hist4[2][tid], t3 = hist4[3][tid];
    const int tot = t0 + t1 + t2 + t3;
    int b = (tot > 0) ? atomicAdd(&gcursor[tid], tot) : 0;
    hist4[0][tid] = b;
    hist4[1][tid] = b + t0;
    hist4[2][tid] = b + t0 + t1;
    hist4[3][tid] = b + t0 + t1 + t2;
  }
  __syncthreads();
#pragma unroll
  for (int j = 0; j < 16; ++j) {
    const int i = tid + j * 256;
    if (i < m) {
      const int c = myd[j] >> SHIFT;
      const int pos = atomicAdd(&hist4[w][c], 1);
      const unsigned pk = (unsigned)mys[j] | ((unsigned)(myd[j] & (RN - 1)) << 22);
      __builtin_nontemporal_store(pk, &pairs[pos]);
    }
  }
}

// one block per bucket: LDS histogram -> degrees (dinv, cnt), local scan ->
// rowptr (padded to x16), then scatter srcs + pad with dummy src=n (zero row).
__global__ __launch_bounds__(512) void k_fine(
    const unsigned* __restrict__ pairs, const int* __restrict__ gcursor,
    int* __restrict__ rowptr, int* __restrict__ cnt, float* __restrict__ dinv,
    int* __restrict__ srcs, int n) {
  __shared__ int hist[RN];
  __shared__ int rowL[RN];
  __shared__ int sdata[RN];
  const int c = blockIdx.x;
  const int tid = threadIdx.x;
  const int node0 = c << SHIFT;
  const int nodes = min(RN, n - node0);
  hist[tid] = 0;
  __syncthreads();
  const int beg = c << CAPLOG;
  const int end = gcursor[c];
  for (int i = beg + tid; i < end; i += RN)
    atomicAdd(&hist[pairs[i] >> 22], 1);
  __syncthreads();
  const int deg = hist[tid];
  const int p = (deg + 15) & ~15;  // pad to x16 -> accum runs 16-edge groups
  sdata[tid] = p;
  __syncthreads();
  for (int off = 1; off < RN; off <<= 1) {
    int t = (tid >= off) ? sdata[tid - off] : 0;
    __syncthreads();
    sdata[tid] += t;
    __syncthreads();
  }
  const int rbase = beg + sdata[tid] - p;
  rowL[tid] = rbase;
  hist[tid] = rbase;
  if (tid < nodes) {
    rowptr[node0 + tid] = rbase;
    cnt[node0 + tid] = p;
    dinv[node0 + tid] = fminf(rsqrtf((float)(deg + 1)), 1.0e6f);
  }
  __syncthreads();
  for (int i = beg + tid; i < end; i += RN) {
    const unsigned pr = pairs[i];
    const int pos = atomicAdd(&hist[pr >> 22], 1);
    srcs[pos] = (int)(pr & 0x3FFFFFu);
  }
  __syncthreads();
  const int fend = rowL[tid] + p;
  for (int i = hist[tid]; i < fend; ++i) srcs[i] = n;  // dummy -> zero row
}

// g(bf16) = (x @ W^T + b) * dinv[r] via mfma_f32_32x32x16_bf16.
// Operand order: A=W-frag, B=x-frag -> lane holds one x-row, regs hold 4
// consecutive cols -> packed uint2 epilogue stores (16/thread, not 64 scalar).
__global__ __launch_bounds__(256) void k_gemm(
    const float* __restrict__ x, const unsigned short* __restrict__ Wbf,
    const float* __restrict__ bias, const float* __restrict__ dinv,
    __hip_bfloat16* __restrict__ g, int n) {
  __shared__ unsigned short xs[128 * 128];
  __shared__ unsigned short Ws[128 * 128];
  const int tid = threadIdx.x;
  const int row0 = blockIdx.x * 128;

#pragma unroll
  for (int u = 0; u < 8; ++u) {
    const int f = tid + 256 * u;
    const int row = f >> 4;
    const int c = f & 15;
    const int ch = (c ^ (row & 7)) << 3;
    // W tile: pre-converted bf16, straight uint4 copy
    *reinterpret_cast<uint4*>(&Ws[row * 128 + ch]) =
        *reinterpret_cast<const uint4*>(&Wbf[row * 128 + c * 8]);
    // x tile: f32 -> bf16 convert + pack
    float4 v0 = make_float4(0.f, 0.f, 0.f, 0.f), v1 = v0;
    if (row0 + row < n) {
      const float4* p =
          reinterpret_cast<const float4*>(&x[(size_t)(row0 + row) * D + c * 8]);
      v0 = p[0]; v1 = p[1];
    }
    uint4 pk;
    pk.x = f2bf(v0.x) | ((unsigned)f2bf(v0.y) << 16);
    pk.y = f2bf(v0.z) | ((unsigned)f2bf(v0.w) << 16);
    pk.z = f2bf(v1.x) | ((unsigned)f2bf(v1.y) << 16);
    pk.w = f2bf(v1.z) | ((unsigned)f2bf(v1.w) << 16);
    *reinterpret_cast<uint4*>(&xs[row * 128 + ch]) = pk;
  }
  __syncthreads();

  const int lane = tid & 63;
  const int wv = tid >> 6;
  const int xr0 = (wv >> 1) * 64;  // x-row tile offset
  const int cc0 = (wv & 1) * 64;   // col tile offset
  const int lr = lane & 31;
  const int lk = lane >> 5;

  f32x16 acc[2][2];  // [p: col subtile][q: row subtile]
#pragma unroll
  for (int p = 0; p < 2; ++p)
#pragma unroll
    for (int q = 0; q < 2; ++q)
#pragma unroll
      for (int t = 0; t < 16; ++t) acc[p][q][t] = 0.f;

#pragma unroll
  for (int ks = 0; ks < 8; ++ks) {
    bf16x8 a[2], b[2];
#pragma unroll
    for (int p = 0; p < 2; ++p) {
      const int r = cc0 + p * 32 + lr;  // W row (output col)
      const int ch = ((ks * 2 + lk) ^ (r & 7)) << 3;
      a[p] = *reinterpret_cast<const bf16x8*>(&Ws[r * 128 + ch]);
    }
#pragma unroll
    for (int q = 0; q < 2; ++q) {
      const int r = xr0 + q * 32 + lr;  // x row
      const int ch = ((ks * 2 + lk) ^ (r & 7)) << 3;
      b[q] = *reinterpret_cast<const bf16x8*>(&xs[r * 128 + ch]);
    }
#pragma unroll
    for (int p = 0; p < 2; ++p)
#pragma unroll
      for (int q = 0; q < 2; ++q)
        acc[p][q] = __builtin_amdgcn_mfma_f32_32x32x16_bf16(a[p], b[q], acc[p][q], 0, 0, 0);
  }

  // D layout: lane = x-row (q*32+lr), reg -> col (reg&3) + 8*(reg>>2) + 4*lk
#pragma unroll
  for (int q = 0; q < 2; ++q) {
    const int r = row0 + xr0 + q * 32 + lr;
    if (r < n) {
      const float dv = dinv[r];
#pragma unroll
      for (int p = 0; p < 2; ++p) {
#pragma unroll
        for (int rg = 0; rg < 4; ++rg) {
          const int cb = cc0 + p * 32 + 8 * rg + 4 * lk;
          const float v0 = (acc[p][q][rg * 4 + 0] + bias[cb + 0]) * dv;
          const float v1 = (acc[p][q][rg * 4 + 1] + bias[cb + 1]) * dv;
          const float v2 = (acc[p][q][rg * 4 + 2] + bias[cb + 2]) * dv;
          const float v3 = (acc[p][q][rg * 4 + 3] + bias[cb + 3]) * dv;
          uint2 pk;
          pk.x = f2bf(v0) | ((unsigned)f2bf(v1) << 16);
          pk.y = f2bf(v2) | ((unsigned)f2bf(v3) << 16);
          *reinterpret_cast<uint2*>(&g[(size_t)r * D + cb]) = pk;
        }
      }
    }
  }
}

// one wave per node; 16-edge groups: half 0 (lanes 0-31) gathers even edges,
// half 1 odd edges, 8B/lane -> 8 independent gathers in flight. srcs for the
// NEXT group prefetched (int4 x4) during current gathers. num % 16 == 0.
__global__ __launch_bounds__(256) void k_accum(
    const int* __restrict__ rowptr, const int* __restrict__ cnt,
    const int* __restrict__ srcs, const uint2* __restrict__ gq,
    const float* __restrict__ dinv, float* __restrict__ out, int n) {
  const int w = (int)(((size_t)blockIdx.x * 256 + threadIdx.x) >> 6);
  const int lane = threadIdx.x & 63;
  if (w >= n) return;
  const int li = lane & 31;
  const int half = lane >> 5;
  const int beg = rowptr[w];
  const int num = cnt[w];

  // self term: half0 reads row w, half1 reads zero row n
  const uint2 sv = gq[(size_t)(half ? n : w) * 32 + li];
  float a0 = bflo(sv.x), a1 = bfhi(sv.x), a2 = bflo(sv.y), a3 = bfhi(sv.y);

  if (num > 0) {
    const int4* s4 = (const int4*)(srcs + beg);
    int4 q0 = s4[0], q1 = s4[1], q2 = s4[2], q3 = s4[3];
    for (int k = 0; k < num; k += 16) {
      const int nx = (k + 16 < num) ? ((k + 16) >> 2) : 0;  // guarded prefetch
      const int4 n0 = s4[nx], n1 = s4[nx + 1], n2 = s4[nx + 2], n3 = s4[nx + 3];
      const int e0 = half ? q0.y : q0.x, e1 = half ? q0.w : q0.z;
      const int e2 = half ? q1.y : q1.x, e3 = half ? q1.w : q1.z;
      const int e4 = half ? q2.y : q2.x, e5 = half ? q2.w : q2.z;
      const int e6 = half ? q3.y : q3.x, e7 = half ? q3.w : q3.z;
      const uint2 t0 = gq[(size_t)e0 * 32 + li];
      const uint2 t1 = gq[(size_t)e1 * 32 + li];
      const uint2 t2 = gq[(size_t)e2 * 32 + li];
      const uint2 t3 = gq[(size_t)e3 * 32 + li];
      const uint2 t4 = gq[(size_t)e4 * 32 + li];
      const uint2 t5 = gq[(size_t)e5 * 32 + li];
      const uint2 t6 = gq[(size_t)e6 * 32 + li];
      const uint2 t7 = gq[(size_t)e7 * 32 + li];
      a0 += bflo(t0.x) + bflo(t1.x) + bflo(t2.x) + bflo(t3.x) +
            bflo(t4.x) + bflo(t5.x) + bflo(t6.x) + bflo(t7.x);
      a1 += bfhi(t0.x) + bfhi(t1.x) + bfhi(t2.x) + bfhi(t3.x) +
            bfhi(t4.x) + bfhi(t5.x) + bfhi(t6.x) + bfhi(t7.x);
      a2 += bflo(t0.y) + bflo(t1.y) + bflo(t2.y) + bflo(t3.y) +
            bflo(t4.y) + bflo(t5.y) + bflo(t6.y) + bflo(t7.y);
      a3 += bfhi(t0.y) + bfhi(t1.y) + bfhi(t2.y) + bfhi(t3.y) +
            bfhi(t4.y) + bfhi(t5.y) + bfhi(t6.y) + bfhi(t7.y);
      q0 = n0; q1 = n1; q2 = n2; q3 = n3;
    }
  }

  a0 += __shfl_xor(a0, 32);
  a1 += __shfl_xor(a1, 32);
  a2 += __shfl_xor(a2, 32);
  a3 += __shfl_xor(a3, 32);

  if (!half) {
    const float dv = dinv[w];
    f32x4 res;
    res[0] = a0 * dv; res[1] = a1 * dv; res[2] = a2 * dv; res[3] = a3 * dv;
    f32x4* dst = (f32x4*)(out + (size_t)w * D) + li;
    __builtin_nontemporal_store(res, dst);
  }
}

extern "C" void kernel_launch(void* const* d_in, const int* in_sizes, int n_in,
                              void* d_out, int out_size, void* d_ws, size_t ws_size,
                              hipStream_t stream) {
  const float* x = (const float*)d_in[0];
  const int* ei = (const int*)d_in[1];
  const float* W = (const float*)d_in[2];
  const float* b = (const float*)d_in[3];
  float* out = (float*)d_out;
  const int n = in_sizes[0] / D;
  const int e = in_sizes[1] / 2;
  const int* src = ei;      // edge_index[0]
  const int* dst = ei + e;  // edge_index[1]
  const int nc = (n + RN - 1) >> SHIFT;  // coarse buckets (196 for n=100k)

  char* ws = (char*)d_ws;
  const size_t nbb = ((size_t)n * 4 + 255) / 256 * 256;
  const size_t pb = (((size_t)nc << CAPLOG) * 4 + 255) / 256 * 256;
  float* dinv = (float*)ws;                         // n
  int* rowptr = (int*)(ws + nbb);                   // n
  int* cnt = (int*)(ws + 2 * nbb);                  // n (padded degree)
  int* gcursor = (int*)(ws + 3 * nbb);              // <=256 (1 KB)
  unsigned short* Wbf = (unsigned short*)(ws + 3 * nbb + 1024);  // 32 KB
  int* srcs = (int*)(ws + 3 * nbb + 1024 + 32768);  // nc*CAP ints
  char* pr_base = ws + 3 * nbb + 1024 + 32768 + pb;
  unsigned* pairs = (unsigned*)pr_base;             // nc*CAP uints (dead after fine)
  // g aliases pairs (gemm runs after fine); (n+1) rows, row n = zeros
  __hip_bfloat16* g = (__hip_bfloat16*)pr_base;

  k_init<<<64, 256, 0, stream>>>(gcursor, nc, (unsigned*)(g + (size_t)n * D), W, Wbf);
  k_psort<<<(e + 4095) / 4096, 256, 0, stream>>>(src, dst, gcursor, pairs, e, nc);
  k_fine<<<nc, RN, 0, stream>>>(pairs, gcursor, rowptr, cnt, dinv, srcs, n);
  k_gemm<<<(n + 127) / 128, 256, 0, stream>>>(x, Wbf, b, dinv, g, n);
  k_accum<<<(n + 3) / 4, 256, 0, stream>>>(rowptr, cnt, srcs, (const uint2*)g,
                                           dinv, out, n);
}